// Round 3
// baseline (926.852 us; speedup 1.0000x reference)
//
#include <hip/hip_runtime.h>
#include <cstdint>

typedef float float2v __attribute__((ext_vector_type(2)));

__device__ inline float2v mk2(float a, float b) { float2v r; r[0] = a; r[1] = b; return r; }

__device__ inline float fast_exp2(float x) {
#if __has_builtin(__builtin_amdgcn_exp2f)
  return __builtin_amdgcn_exp2f(x);
#else
  return exp2f(x);
#endif
}
__device__ inline float fast_rcp(float x) {
#if __has_builtin(__builtin_amdgcn_rcpf)
  return __builtin_amdgcn_rcpf(x);
#else
  return 1.0f / x;
#endif
}

#define BB 256
#define SS 4096
#define II 32
#define HH 64
// Segmented scan (validated: contractive recurrence, 32-step warmup error
// ~0.16^32). Input projection fused (round 2). Round 3 fix: rounds 1-2 both
// showed VGPR_Count < 96 => the compiler REMATERIALIZED the W_hh/Wc register
// arrays as per-step global loads on the serial chain (795us). The empty
// "+v" asm below makes each loaded weight opaque so regalloc must keep it
// VGPR-resident (96 pinned + ~50 working < 168 budget at 3 waves/SIMD).
#define SEGS 32
#define SEGLEN 128
#define WU 32
#define CH 8
#define WPB 4  // streams (waves) per block

#define PIN(v) asm volatile("" : "+v"(v))

// ---------------- prep: Wc = W_ih @ W_in  [64][32], bc = W_ih@b_in + bias ----------------
__global__ __launch_bounds__(256) void prep_kernel(
    const float* __restrict__ W_in, const float* __restrict__ b_in,
    const float* __restrict__ W_ih, const float* __restrict__ bias,
    float* __restrict__ Wc, float* __restrict__ bc) {
  int tid = threadIdx.x;
  int j = tid & 63;
  int iq = tid >> 6;  // 0..3, each handles 8 of the 32 input cols
  float acc[8];
#pragma unroll
  for (int i = 0; i < 8; ++i) acc[i] = 0.f;
  const float* wih = W_ih + j * HH;
  for (int h = 0; h < HH; ++h) {
    float w = wih[h];
    const float* wr = W_in + h * II + iq * 8;
#pragma unroll
    for (int i = 0; i < 8; ++i) acc[i] = fmaf(w, wr[i], acc[i]);
  }
#pragma unroll
  for (int i = 0; i < 8; ++i) Wc[j * II + iq * 8 + i] = acc[i];
  if (iq == 0) {
    float s = 0.f;
    for (int h = 0; h < HH; ++h) s = fmaf(wih[h], b_in[h], s);
    bc[j] = s + bias[j];
  }
}

// ---------------- fused scan: input proj + recurrence + output GEMV ----------------
__global__ __launch_bounds__(256, 3) void fused_scan_kernel(
    const float* __restrict__ x, const float* __restrict__ Wc,
    const float* __restrict__ bc, const float* __restrict__ W_hh,
    const float* __restrict__ tau, const float* __restrict__ W_out,
    const float* __restrict__ b_out, float* __restrict__ out) {
  __shared__ __align__(16) float tbuf[WPB][CH * 68];  // per-wave tanh ring (8 steps x 64, +4 pad)
  __shared__ __align__(16) float woutl[64];
  int lane = threadIdx.x & 63;
  int w = threadIdx.x >> 6;
  int idx = blockIdx.x * WPB + w;  // stream id
  int b = idx >> 5;
  int s = idx & (SEGS - 1);
  int warmCh = s ? (WU / CH) : 0;       // 4 warmup chunks (0 for segment 0)
  int nCh = SEGLEN / CH + warmCh;       // 16 or 20
  long t0 = (long)s * SEGLEN - (s ? WU : 0);
  const float* xs = x + ((size_t)b * SS + (size_t)t0) * II;
  float* outb = out + (size_t)b * SS + (size_t)s * SEGLEN;

  // W_hh row for this lane's hidden unit: 32 float2 pairs (64 VGPRs)
  float2v w2[32];
  {
    const float4* wr = (const float4*)(W_hh + lane * HH);
#pragma unroll
    for (int i = 0; i < 16; ++i) {
      float4 q = wr[i];
      w2[2 * i] = mk2(q.x, q.y);
      w2[2 * i + 1] = mk2(q.z, q.w);
    }
  }
  // Wc row (input projection weights): 16 float2 pairs (32 VGPRs)
  float2v wc2[16];
  {
    const float4* wr = (const float4*)(Wc + lane * II);
#pragma unroll
    for (int i = 0; i < 8; ++i) {
      float4 q = wr[i];
      wc2[2 * i] = mk2(q.x, q.y);
      wc2[2 * i + 1] = mk2(q.z, q.w);
    }
  }
  // Pin: values become opaque -> cannot be rematerialized as in-loop reloads.
#pragma unroll
  for (int i = 0; i < 32; ++i) PIN(w2[i]);
#pragma unroll
  for (int i = 0; i < 16; ++i) PIN(wc2[i]);

  float cinv = 1.0f / tau[lane];  // dt = 1.0
  float aco = 1.0f - cinv;
  float bcv = bc[lane];
  woutl[lane] = W_out[lane];  // all waves write identical values: benign
  float bout = b_out[0];
  float* tb = tbuf[w];
  tb[(CH - 1) * 68 + lane] = 0.0f;  // tanh(h_{t0-1}) = 0
  __syncthreads();

  float h = 0.0f;
  for (int c = 0; c < nCh; ++c) {
#pragma unroll
    for (int r = 0; r < CH; ++r) {
      // ---- input projection: x_t (wave-uniform row, 8x float4) . Wc[lane]
      const float4* xr = (const float4*)xs;
      float2v xa0 = mk2(0, 0), xa1 = mk2(0, 0), xa2 = mk2(0, 0), xa3 = mk2(0, 0);
#pragma unroll
      for (int i = 0; i < 8; i += 2) {
        float4 q = xr[i];
        float4 p = xr[i + 1];
        xa0 += mk2(q.x, q.y) * wc2[2 * i];
        xa1 += mk2(q.z, q.w) * wc2[2 * i + 1];
        xa2 += mk2(p.x, p.y) * wc2[2 * i + 2];
        xa3 += mk2(p.z, p.w) * wc2[2 * i + 3];
      }
      // ---- recurrent matvec: broadcast-read tanh(h_{t-1}) from the ring
      const float4* trow = (const float4*)(tb + ((r + CH - 1) & (CH - 1)) * 68);
      float2v a0 = mk2(0, 0), a1 = mk2(0, 0), a2 = mk2(0, 0), a3 = mk2(0, 0);
#pragma unroll
      for (int i = 0; i < 16; i += 2) {
        float4 q = trow[i];
        float4 p = trow[i + 1];
        a0 += mk2(q.x, q.y) * w2[2 * i];
        a1 += mk2(q.z, q.w) * w2[2 * i + 1];
        a2 += mk2(p.x, p.y) * w2[2 * i + 2];
        a3 += mk2(p.z, p.w) * w2[2 * i + 3];
      }
      float2v aa = ((a0 + a1) + (a2 + a3)) + ((xa0 + xa1) + (xa2 + xa3));
      float dot = aa[0] + aa[1];
      h = fmaf(aco, h, cinv * (dot + bcv));
      // tanh(h) = 1 - 2/(exp2(2*log2e*h)+1); saturates correctly at +/-inf
      float e = fast_exp2(h * 2.885390081777927f);
      float tv = 1.0f - 2.0f * fast_rcp(e + 1.0f);
      tb[r * 68 + lane] = tv;
      xs += II;
    }
    // ---- fused output GEMV for this chunk (skip warmup chunks)
    int rc = c - warmCh;
    if (rc >= 0) {
      int rr = lane & 7;   // step within chunk
      int g = lane >> 3;   // hidden octant
      const float4* tr = (const float4*)(tb + rr * 68 + g * 8);
      const float4* wl = (const float4*)(woutl + g * 8);
      float4 q0 = tr[0], q1 = tr[1];
      float4 u0 = wl[0], u1 = wl[1];
      float2v s0 = mk2(q0.x, q0.y) * mk2(u0.x, u0.y) + mk2(q0.z, q0.w) * mk2(u0.z, u0.w);
      s0 += mk2(q1.x, q1.y) * mk2(u1.x, u1.y) + mk2(q1.z, q1.w) * mk2(u1.z, u1.w);
      float v = s0[0] + s0[1];
      v += __shfl_xor(v, 8);
      v += __shfl_xor(v, 16);
      v += __shfl_xor(v, 32);
      if (lane < 8) outb[rc * CH + lane] = v + bout;
    }
  }
}

extern "C" void kernel_launch(void* const* d_in, const int* in_sizes, int n_in,
                              void* d_out, int out_size, void* d_ws, size_t ws_size,
                              hipStream_t stream) {
  const float* x     = (const float*)d_in[0];
  const float* W_in  = (const float*)d_in[1];
  const float* b_in  = (const float*)d_in[2];
  const float* W_hh  = (const float*)d_in[3];
  const float* W_ih  = (const float*)d_in[4];
  const float* bias  = (const float*)d_in[5];
  const float* tau   = (const float*)d_in[6];
  const float* W_out = (const float*)d_in[7];
  const float* b_out = (const float*)d_in[8];
  float* out = (float*)d_out;
  char* ws = (char*)d_ws;
  float* Wc = (float*)ws;            // 8 KB
  float* bc = (float*)(ws + 8192);   // 256 B

  hipLaunchKernelGGL(prep_kernel, dim3(1), dim3(256), 0, stream,
                     W_in, b_in, W_ih, bias, Wc, bc);
  hipLaunchKernelGGL(fused_scan_kernel, dim3(BB * SEGS / WPB), dim3(256), 0, stream,
                     x, Wc, bc, W_hh, tau, W_out, b_out, out);
}

// Round 4
// 434.407 us; speedup vs baseline: 2.1336x; 2.1336x over previous
//
#include <hip/hip_runtime.h>
#include <cstdint>

typedef float float2v __attribute__((ext_vector_type(2)));

__device__ inline float2v mk2(float a, float b) { float2v r; r[0] = a; r[1] = b; return r; }

__device__ inline float fast_exp2(float x) {
#if __has_builtin(__builtin_amdgcn_exp2f)
  return __builtin_amdgcn_exp2f(x);
#else
  return exp2f(x);
#endif
}
__device__ inline float fast_rcp(float x) {
#if __has_builtin(__builtin_amdgcn_rcpf)
  return __builtin_amdgcn_rcpf(x);
#else
  return 1.0f / x;
#endif
}

#define BB 256
#define SS 4096
#define II 32
#define HH 64
// Segmented scan (validated: contractive recurrence, 32-step warmup, error
// ~0.16^32). Fused input projection (round 2, numerically validated).
// Round 4 fix: rounds 2-3 failed because __launch_bounds__(256,3) gave only
// a 168-VGPR budget; the unrolled step body peaks ~190 regs, so regalloc
// SPILLED the longest live ranges -- the 96 weight registers -- to scratch,
// reloading them every serial step (3750 cy/step measured). PIN blocks
// remat, not spills. Fix: 1-wave blocks + __launch_bounds__(64,2) = 256-reg
// budget -> zero spills; x staged chunk-granular through LDS (1 float4/lane
// covers 8 steps, issued a full chunk ahead -> HBM first-touch hidden).
#define SEGS 32
#define SEGLEN 128
#define WU 32
#define CH 8

#define PIN(v) asm volatile("" : "+v"(v))

// ---------------- prep: Wc = W_ih @ W_in  [64][32], bc = W_ih@b_in + bias ----------------
__global__ __launch_bounds__(256) void prep_kernel(
    const float* __restrict__ W_in, const float* __restrict__ b_in,
    const float* __restrict__ W_ih, const float* __restrict__ bias,
    float* __restrict__ Wc, float* __restrict__ bc) {
  int tid = threadIdx.x;
  int j = tid & 63;
  int iq = tid >> 6;  // 0..3, each handles 8 of the 32 input cols
  float acc[8];
#pragma unroll
  for (int i = 0; i < 8; ++i) acc[i] = 0.f;
  const float* wih = W_ih + j * HH;
  for (int h = 0; h < HH; ++h) {
    float w = wih[h];
    const float* wr = W_in + h * II + iq * 8;
#pragma unroll
    for (int i = 0; i < 8; ++i) acc[i] = fmaf(w, wr[i], acc[i]);
  }
#pragma unroll
  for (int i = 0; i < 8; ++i) Wc[j * II + iq * 8 + i] = acc[i];
  if (iq == 0) {
    float s = 0.f;
    for (int h = 0; h < HH; ++h) s = fmaf(wih[h], b_in[h], s);
    bc[j] = s + bias[j];
  }
}

// ---------------- fused scan: one wave per (batch,segment) ----------------
__global__ __launch_bounds__(64, 2) void fused_scan_kernel(
    const float* __restrict__ x, const float* __restrict__ Wc,
    const float* __restrict__ bc, const float* __restrict__ W_hh,
    const float* __restrict__ tau, const float* __restrict__ W_out,
    const float* __restrict__ b_out, float* __restrict__ out) {
  __shared__ __align__(16) float tbuf[CH * 68];   // tanh ring: 8 steps x 64 (+4 pad)
  __shared__ __align__(16) float4 xbuf[64];       // one 8-step x chunk (8 x 8 float4)
  __shared__ __align__(16) float woutl[64];
  int lane = threadIdx.x;
  int idx = blockIdx.x;
  int b = idx >> 5;
  int s = idx & (SEGS - 1);
  int warmCh = s ? (WU / CH) : 0;       // 4 warmup chunks (0 for segment 0)
  int nCh = SEGLEN / CH + warmCh;       // 16 or 20
  long t0 = (long)s * SEGLEN - (s ? WU : 0);
  const float4* xs4 = (const float4*)(x + ((size_t)b * SS + (size_t)t0) * II);
  float* outb = out + (size_t)b * SS + (size_t)s * SEGLEN;

  // W_hh row for this lane's hidden unit: 32 float2 pairs (64 VGPRs)
  float2v w2[32];
  {
    const float4* wr = (const float4*)(W_hh + lane * HH);
#pragma unroll
    for (int i = 0; i < 16; ++i) {
      float4 q = wr[i];
      w2[2 * i] = mk2(q.x, q.y);
      w2[2 * i + 1] = mk2(q.z, q.w);
    }
  }
  // Wc row (input projection weights): 16 float2 pairs (32 VGPRs)
  float2v wc2[16];
  {
    const float4* wr = (const float4*)(Wc + lane * II);
#pragma unroll
    for (int i = 0; i < 8; ++i) {
      float4 q = wr[i];
      wc2[2 * i] = mk2(q.x, q.y);
      wc2[2 * i + 1] = mk2(q.z, q.w);
    }
  }
#pragma unroll
  for (int i = 0; i < 32; ++i) PIN(w2[i]);
#pragma unroll
  for (int i = 0; i < 16; ++i) PIN(wc2[i]);

  float cinv = 1.0f / tau[lane];  // dt = 1.0
  float aco = 1.0f - cinv;
  float bcv = bc[lane];
  woutl[lane] = W_out[lane];
  float bout = b_out[0];
  tbuf[(CH - 1) * 68 + lane] = 0.0f;  // tanh(h_{t0-1}) = 0
  // prologue: stage x chunk 0 (8 steps x 128 B = 1 float4 per lane, coalesced)
  xbuf[lane] = xs4[lane];

  float h = 0.0f;
  for (int c = 0; c < nCh; ++c) {
    // register-prefetch next x chunk (issued ~8 steps (~1600 cy) before use)
    float4 nxt;
    if (c + 1 < nCh) nxt = xs4[(size_t)(c + 1) * 64 + lane];
#pragma unroll
    for (int r = 0; r < CH; ++r) {
      const float4* xr = (const float4*)xbuf + r * 8;  // wave-uniform broadcast
      const float4* trow = (const float4*)(tbuf + ((r + CH - 1) & (CH - 1)) * 68);
      float2v a0 = mk2(0, 0), a1 = mk2(0, 0), a2 = mk2(0, 0), a3 = mk2(0, 0);
      // input projection: x_t . Wc[lane]
#pragma unroll
      for (int i = 0; i < 8; i += 2) {
        float4 q = xr[i];
        float4 p = xr[i + 1];
        a0 += mk2(q.x, q.y) * wc2[2 * i];
        a1 += mk2(q.z, q.w) * wc2[2 * i + 1];
        a2 += mk2(p.x, p.y) * wc2[2 * i + 2];
        a3 += mk2(p.z, p.w) * wc2[2 * i + 3];
      }
      // recurrent matvec: tanh(h_{t-1}) broadcast from ring
#pragma unroll
      for (int i = 0; i < 16; i += 2) {
        float4 q = trow[i];
        float4 p = trow[i + 1];
        a0 += mk2(q.x, q.y) * w2[2 * i];
        a1 += mk2(q.z, q.w) * w2[2 * i + 1];
        a2 += mk2(p.x, p.y) * w2[2 * i + 2];
        a3 += mk2(p.z, p.w) * w2[2 * i + 3];
      }
      float2v aa = (a0 + a1) + (a2 + a3);
      float dot = aa[0] + aa[1];
      h = fmaf(aco, h, cinv * (dot + bcv));
      // tanh(h) = 1 - 2/(exp2(2*log2e*h)+1); saturates correctly at +/-inf
      float e = fast_exp2(h * 2.885390081777927f);
      float tv = 1.0f - 2.0f * fast_rcp(e + 1.0f);
      tbuf[r * 68 + lane] = tv;
    }
    // fused output GEMV for this chunk (skip warmup chunks)
    int rc = c - warmCh;
    if (rc >= 0) {
      int rr = lane & 7;   // step within chunk
      int g = lane >> 3;   // hidden octant
      const float4* tr = (const float4*)(tbuf + rr * 68 + g * 8);
      const float4* wl = (const float4*)(woutl + g * 8);
      float4 q0 = tr[0], q1 = tr[1];
      float4 u0 = wl[0], u1 = wl[1];
      float2v s0 = mk2(q0.x, q0.y) * mk2(u0.x, u0.y) + mk2(q0.z, q0.w) * mk2(u0.z, u0.w);
      s0 += mk2(q1.x, q1.y) * mk2(u1.x, u1.y) + mk2(q1.z, q1.w) * mk2(u1.z, u1.w);
      float v = s0[0] + s0[1];
      v += __shfl_xor(v, 8);
      v += __shfl_xor(v, 16);
      v += __shfl_xor(v, 32);
      if (lane < 8) outb[rc * CH + lane] = v + bout;
    }
    // stage prefetched x chunk (single wave: in-order LDS ops, no barrier needed)
    if (c + 1 < nCh) xbuf[lane] = nxt;
  }
}

extern "C" void kernel_launch(void* const* d_in, const int* in_sizes, int n_in,
                              void* d_out, int out_size, void* d_ws, size_t ws_size,
                              hipStream_t stream) {
  const float* x     = (const float*)d_in[0];
  const float* W_in  = (const float*)d_in[1];
  const float* b_in  = (const float*)d_in[2];
  const float* W_hh  = (const float*)d_in[3];
  const float* W_ih  = (const float*)d_in[4];
  const float* bias  = (const float*)d_in[5];
  const float* tau   = (const float*)d_in[6];
  const float* W_out = (const float*)d_in[7];
  const float* b_out = (const float*)d_in[8];
  float* out = (float*)d_out;
  char* ws = (char*)d_ws;
  float* Wc = (float*)ws;            // 8 KB
  float* bc = (float*)(ws + 8192);   // 256 B

  hipLaunchKernelGGL(prep_kernel, dim3(1), dim3(256), 0, stream,
                     W_in, b_in, W_ih, bias, Wc, bc);
  hipLaunchKernelGGL(fused_scan_kernel, dim3(BB * SEGS), dim3(64), 0, stream,
                     x, Wc, bc, W_hh, tau, W_out, b_out, out);
}

// Round 5
// 248.683 us; speedup vs baseline: 3.7270x; 1.7468x over previous
//
#include <hip/hip_runtime.h>
#include <hip/hip_bf16.h>
#include <cstdint>

typedef float f32x4 __attribute__((ext_vector_type(4)));
typedef short bf16x8 __attribute__((ext_vector_type(8)));
typedef short s16x4 __attribute__((ext_vector_type(4)));

#define BB 256
#define SS 4096
#define II 32
#define HH 64
// 16 streams per wave via MFMA (swapped orientation: D[j][s], stream = MFMA
// column -> streams never mix). SEGLEN=32 + WU=16 warmup (contraction 0.16 ->
// 0.16^16 ~ 1e-13 init error). 32768 streams = 2048 waves = 2/SIMD.
// Rounds 1-4 lesson: scalar-FMA formulations die on weight-register spill
// (VGPR stuck at 68, weights reloaded per serial step). MFMA fragments (48
// VGPRs) are consumed directly by the matrix pipe - nothing to spill.
#define SEGLEN 32
#define WU 16

__device__ inline float fast_exp2(float x) {
#if __has_builtin(__builtin_amdgcn_exp2f)
  return __builtin_amdgcn_exp2f(x);
#else
  return exp2f(x);
#endif
}
__device__ inline float fast_rcp(float x) {
#if __has_builtin(__builtin_amdgcn_rcpf)
  return __builtin_amdgcn_rcpf(x);
#else
  return 1.0f / x;
#endif
}
__device__ inline unsigned short bfr(float f) {
  return __builtin_bit_cast(unsigned short, __float2bfloat16(f));
}
__device__ inline bf16x8 pk8(f32x4 a, f32x4 b) {
  bf16x8 r;
  r[0] = (short)bfr(a[0]); r[1] = (short)bfr(a[1]);
  r[2] = (short)bfr(a[2]); r[3] = (short)bfr(a[3]);
  r[4] = (short)bfr(b[0]); r[5] = (short)bfr(b[1]);
  r[6] = (short)bfr(b[2]); r[7] = (short)bfr(b[3]);
  return r;
}

// ---------------- prep: Wc = W_ih @ W_in  [64][32], bc = W_ih@b_in + bias ----------------
__global__ __launch_bounds__(256) void prep_kernel(
    const float* __restrict__ W_in, const float* __restrict__ b_in,
    const float* __restrict__ W_ih, const float* __restrict__ bias,
    float* __restrict__ Wc, float* __restrict__ bc) {
  int tid = threadIdx.x;
  int j = tid & 63;
  int iq = tid >> 6;
  float acc[8];
#pragma unroll
  for (int i = 0; i < 8; ++i) acc[i] = 0.f;
  const float* wih = W_ih + j * HH;
  for (int h = 0; h < HH; ++h) {
    float w = wih[h];
    const float* wr = W_in + h * II + iq * 8;
#pragma unroll
    for (int i = 0; i < 8; ++i) acc[i] = fmaf(w, wr[i], acc[i]);
  }
#pragma unroll
  for (int i = 0; i < 8; ++i) Wc[j * II + iq * 8 + i] = acc[i];
  if (iq == 0) {
    float s = 0.f;
    for (int h = 0; h < HH; ++h) s = fmaf(wih[h], b_in[h], s);
    bc[j] = s + bias[j];
  }
}

// ---------------- fused MFMA scan: 16 streams per wave ----------------
// Fragment maps (gfx950, 16x16x32 bf16):
//   A[row][k]: row = lane&15 (+16*m-tile), k = kt*16-block: k = 16*g + 4*(lane>>4) + e  (elem = 4g+e)
//   B[k][n]:   n  = lane&15, same k map
//   C/D:       col = lane&15, row = 4*(lane>>4) + reg (+16*m-tile)   [m89 verified]
__global__ __launch_bounds__(64, 2) void fused_scan_kernel(
    const float* __restrict__ x, const float* __restrict__ Wc,
    const float* __restrict__ bc, const float* __restrict__ W_hh,
    const float* __restrict__ tau, const float* __restrict__ W_out,
    const float* __restrict__ b_out, float* __restrict__ out) {
  __shared__ __align__(16) unsigned short Tb[16][72];  // T[stream][hidden] bf16, 144B rows
  int l = threadIdx.x;
  int c = l & 15, r0 = l >> 4;
  int blk = blockIdx.x;
  int b = blk >> 3;          // batch
  int g = blk & 7;           // 16-segment group within batch

  // zero T (tanh(h_init)=0 for all streams)
  {
    uint32_t* tz = (uint32_t*)&Tb[0][0];
#pragma unroll
    for (int i = 0; i < 9; ++i) tz[i * 64 + l] = 0u;
  }

  // W_hh A-fragments: row j = 16*m0 + c, k groups {4r0..+3, 16+4r0..+3} per 32-K tile
  bf16x8 Ahh[4][2];
#pragma unroll
  for (int m0 = 0; m0 < 4; ++m0)
#pragma unroll
    for (int kt = 0; kt < 2; ++kt) {
      const float* p = W_hh + (size_t)(16 * m0 + c) * HH + kt * 32 + 4 * r0;
      Ahh[m0][kt] = pk8(*(const f32x4*)p, *(const f32x4*)(p + 16));
    }
  // Wc A-fragments (input projection, K=32 exactly)
  bf16x8 Ac[4];
#pragma unroll
  for (int m0 = 0; m0 < 4; ++m0) {
    const float* p = Wc + (size_t)(16 * m0 + c) * II + 4 * r0;
    Ac[m0] = pk8(*(const f32x4*)p, *(const f32x4*)(p + 16));
  }
  // per-lane j-coefficients: j = 16*m0 + 4*r0 + r
  f32x4 bc4[4], ci4[4], ac4[4], wo4[4], h[4];
#pragma unroll
  for (int m0 = 0; m0 < 4; ++m0) {
    int j0 = 16 * m0 + 4 * r0;
    bc4[m0] = *(const f32x4*)(bc + j0);
    f32x4 tv = *(const f32x4*)(tau + j0);
    f32x4 ci, ao, z;
#pragma unroll
    for (int r = 0; r < 4; ++r) { ci[r] = 1.0f / tv[r]; ao[r] = 1.0f - ci[r]; z[r] = 0.0f; }
    ci4[m0] = ci; ac4[m0] = ao; h[m0] = z;
    wo4[m0] = *(const f32x4*)(W_out + j0);
  }
  float bout = b_out[0];
  // seg 0 (g==0, stream col 0) has no real warmup: force h=0 through warmup
  float mz = (g == 0 && c == 0) ? 0.0f : 1.0f;

  const float* xb = x + (size_t)b * (SS * II);
  int s32 = (g * 16 + c) * SEGLEN;  // this lane's stream: global t of first real step
  float* outp = out + (size_t)b * SS + (size_t)(g * 16 + l) * SEGLEN;  // lanes<16

  // prime x for tt=0 (warmup step at global t = s32-16, clamped for seg 0)
  f32x4 cxa, cxb;
  {
    int ro = s32 - WU; if (ro < 0) ro = 0;
    const float* p = xb + (size_t)ro * II + 4 * r0;
    cxa = *(const f32x4*)p; cxb = *(const f32x4*)(p + 16);
  }

  for (int tt = 0; tt < WU + SEGLEN; ++tt) {
    // prefetch next step's x row slice (off the serial chain)
    f32x4 nxa, nxb;
    {
      int ro = s32 + tt + 1 - WU;
      if (ro < 0) ro = 0;
      if (ro > SS - 1) ro = SS - 1;
      const float* p = xb + (size_t)ro * II + 4 * r0;
      nxa = *(const f32x4*)p; nxb = *(const f32x4*)(p + 16);
    }
    bf16x8 Bx = pk8(cxa, cxb);  // B[k][s]: x_t[s=c][k-groups]
    // T B-fragments from LDS (written end of previous step)
    bf16x8 Bt[2];
#pragma unroll
    for (int kt = 0; kt < 2; ++kt) {
      s16x4 lo = *(const s16x4*)&Tb[c][kt * 32 + 4 * r0];
      s16x4 hi = *(const s16x4*)&Tb[c][kt * 32 + 16 + 4 * r0];
      Bt[kt] = __builtin_shufflevector(lo, hi, 0, 1, 2, 3, 4, 5, 6, 7);
    }
    float psum = 0.0f;
#pragma unroll
    for (int m0 = 0; m0 < 4; ++m0) {
      f32x4 acc = bc4[m0];  // C-in = bc[j]
      acc = __builtin_amdgcn_mfma_f32_16x16x32_bf16(Ac[m0], Bx, acc, 0, 0, 0);
      acc = __builtin_amdgcn_mfma_f32_16x16x32_bf16(Ahh[m0][0], Bt[0], acc, 0, 0, 0);
      acc = __builtin_amdgcn_mfma_f32_16x16x32_bf16(Ahh[m0][1], Bt[1], acc, 0, 0, 0);
      h[m0] = ac4[m0] * h[m0] + ci4[m0] * acc;
      if (tt < WU) h[m0] = h[m0] * mz;
      s16x4 tp;
#pragma unroll
      for (int r = 0; r < 4; ++r) {
        float e = fast_exp2(h[m0][r] * 2.885390081777927f);
        float t = 1.0f - 2.0f * fast_rcp(e + 1.0f);
        psum = fmaf(wo4[m0][r], t, psum);
        tp[r] = (short)bfr(t);
      }
      // write T[s=c][j=16m0+4r0 .. +3] (4 consecutive bf16, one b64)
      *(s16x4*)&Tb[c][16 * m0 + 4 * r0] = tp;
    }
    if (tt >= WU) {
      psum += __shfl_xor(psum, 16);
      psum += __shfl_xor(psum, 32);
      if (l < 16) outp[tt - WU] = psum + bout;
    }
    cxa = nxa; cxb = nxb;
  }
}

extern "C" void kernel_launch(void* const* d_in, const int* in_sizes, int n_in,
                              void* d_out, int out_size, void* d_ws, size_t ws_size,
                              hipStream_t stream) {
  const float* x     = (const float*)d_in[0];
  const float* W_in  = (const float*)d_in[1];
  const float* b_in  = (const float*)d_in[2];
  const float* W_hh  = (const float*)d_in[3];
  const float* W_ih  = (const float*)d_in[4];
  const float* bias  = (const float*)d_in[5];
  const float* tau   = (const float*)d_in[6];
  const float* W_out = (const float*)d_in[7];
  const float* b_out = (const float*)d_in[8];
  float* out = (float*)d_out;
  char* ws = (char*)d_ws;
  float* Wc = (float*)ws;            // 8 KB
  float* bc = (float*)(ws + 8192);   // 256 B

  hipLaunchKernelGGL(prep_kernel, dim3(1), dim3(256), 0, stream,
                     W_in, b_in, W_ih, bias, Wc, bc);
  // 256 batches x 8 groups of 16 segments; 1 wave per block
  hipLaunchKernelGGL(fused_scan_kernel, dim3(BB * 8), dim3(64), 0, stream,
                     x, Wc, bc, W_hh, tau, W_out, b_out, out);
}

// Round 6
// 242.198 us; speedup vs baseline: 3.8268x; 1.0268x over previous
//
#include <hip/hip_runtime.h>
#include <hip/hip_bf16.h>
#include <cstdint>

typedef float f32x4 __attribute__((ext_vector_type(4)));
typedef short bf16x8 __attribute__((ext_vector_type(8)));
typedef short s16x4 __attribute__((ext_vector_type(4)));

#define BB 256
#define SS 4096
#define II 32
#define HH 64
// 16 streams per wave via MFMA (swapped orientation: D[j][s], stream = MFMA
// column -> streams never mix). Round 6: T (tanh of h) is now fully
// REGISTER-RESIDENT -- the 16x16x32 D-fragment layout (lane holds rows
// 16m0+4r0+r of column c) is exactly the union of the next step's B-fragment
// k-slices (kt*32 + {4r0, 16+4r0}), so Bt[0]=pack(t4[0],t4[1]),
// Bt[1]=pack(t4[2],t4[3]) lane-locally. No LDS at all: the 120-cy
// ds_write->ds_read round-trip and 434K bank conflicts leave the serial
// chain. WU=8 (contraction <=0.16/step -> init error 0.16^8 ~ 4e-7, far
// below the bf16 noise floor; WU=32 and WU=16 measured bit-identical absmax).
#define SEGLEN 32
#define WU 8

#define PINV(v) asm volatile("" : "+v"(v))

__device__ inline float fast_exp2(float x) {
#if __has_builtin(__builtin_amdgcn_exp2f)
  return __builtin_amdgcn_exp2f(x);
#else
  return exp2f(x);
#endif
}
__device__ inline float fast_rcp(float x) {
#if __has_builtin(__builtin_amdgcn_rcpf)
  return __builtin_amdgcn_rcpf(x);
#else
  return 1.0f / x;
#endif
}
__device__ inline unsigned short bfr(float f) {
  return __builtin_bit_cast(unsigned short, __float2bfloat16(f));
}
__device__ inline bf16x8 pk8(f32x4 a, f32x4 b) {
  bf16x8 r;
  r[0] = (short)bfr(a[0]); r[1] = (short)bfr(a[1]);
  r[2] = (short)bfr(a[2]); r[3] = (short)bfr(a[3]);
  r[4] = (short)bfr(b[0]); r[5] = (short)bfr(b[1]);
  r[6] = (short)bfr(b[2]); r[7] = (short)bfr(b[3]);
  return r;
}

// ---------------- prep: Wc = W_ih @ W_in  [64][32], bc = W_ih@b_in + bias ----------------
__global__ __launch_bounds__(256) void prep_kernel(
    const float* __restrict__ W_in, const float* __restrict__ b_in,
    const float* __restrict__ W_ih, const float* __restrict__ bias,
    float* __restrict__ Wc, float* __restrict__ bc) {
  int tid = threadIdx.x;
  int j = tid & 63;
  int iq = tid >> 6;
  float acc[8];
#pragma unroll
  for (int i = 0; i < 8; ++i) acc[i] = 0.f;
  const float* wih = W_ih + j * HH;
  for (int h = 0; h < HH; ++h) {
    float w = wih[h];
    const float* wr = W_in + h * II + iq * 8;
#pragma unroll
    for (int i = 0; i < 8; ++i) acc[i] = fmaf(w, wr[i], acc[i]);
  }
#pragma unroll
  for (int i = 0; i < 8; ++i) Wc[j * II + iq * 8 + i] = acc[i];
  if (iq == 0) {
    float s = 0.f;
    for (int h = 0; h < HH; ++h) s = fmaf(wih[h], b_in[h], s);
    bc[j] = s + bias[j];
  }
}

// ---------------- fused MFMA scan: 16 streams per wave, zero LDS ----------------
// Fragment maps (gfx950, 16x16x32 bf16; validated by passing R5):
//   A[row][k]: row = (lane&15)+16*m-tile; elem e -> k = kt*32 + (e<4 ? 4*(l>>4)+e
//              : 16+4*(l>>4)+e-4)
//   B[k][n]:   n = lane&15, same k map
//   C/D:       col = lane&15, row = 16*m-tile + 4*(lane>>4) + reg
__global__ __launch_bounds__(64, 2) void fused_scan_kernel(
    const float* __restrict__ x, const float* __restrict__ Wc,
    const float* __restrict__ bc, const float* __restrict__ W_hh,
    const float* __restrict__ tau, const float* __restrict__ W_out,
    const float* __restrict__ b_out, float* __restrict__ out) {
  int l = threadIdx.x;
  int c = l & 15, r0 = l >> 4;
  int blk = blockIdx.x;
  int b = blk >> 3;          // batch
  int g = blk & 7;           // 16-segment group within batch

  // W_hh A-fragments
  bf16x8 Ahh[4][2];
#pragma unroll
  for (int m0 = 0; m0 < 4; ++m0)
#pragma unroll
    for (int kt = 0; kt < 2; ++kt) {
      const float* p = W_hh + (size_t)(16 * m0 + c) * HH + kt * 32 + 4 * r0;
      Ahh[m0][kt] = pk8(*(const f32x4*)p, *(const f32x4*)(p + 16));
    }
  // Wc A-fragments (input projection, K=32 exactly)
  bf16x8 Ac[4];
#pragma unroll
  for (int m0 = 0; m0 < 4; ++m0) {
    const float* p = Wc + (size_t)(16 * m0 + c) * II + 4 * r0;
    Ac[m0] = pk8(*(const f32x4*)p, *(const f32x4*)(p + 16));
  }
#pragma unroll
  for (int m0 = 0; m0 < 4; ++m0) {
    PINV(Ahh[m0][0]); PINV(Ahh[m0][1]); PINV(Ac[m0]);
  }
  // per-lane j-coefficients: j = 16*m0 + 4*r0 + r
  f32x4 bc4[4], ci4[4], ac4[4], wo4[4], h[4];
#pragma unroll
  for (int m0 = 0; m0 < 4; ++m0) {
    int j0 = 16 * m0 + 4 * r0;
    bc4[m0] = *(const f32x4*)(bc + j0);
    f32x4 tv = *(const f32x4*)(tau + j0);
    f32x4 ci, ao;
#pragma unroll
    for (int r = 0; r < 4; ++r) { ci[r] = 1.0f / tv[r]; ao[r] = 1.0f - ci[r]; }
    ci4[m0] = ci; ac4[m0] = ao; h[m0] = 0.0f;
    wo4[m0] = *(const f32x4*)(W_out + j0);
  }
  float bout = b_out[0];
  // seg 0 (g==0, stream col 0) has no real history: force h=0 through warmup
  float mz = (g == 0 && c == 0) ? 0.0f : 1.0f;

  const float* xb = x + (size_t)b * (SS * II);
  int s32 = (g * 16 + c) * SEGLEN;  // global t of this lane's first real step
  float* outp = out + (size_t)b * SS + (size_t)(g * 16 + l) * SEGLEN;  // lanes<16

  const int NT = WU + SEGLEN;  // 40
  // x pipeline, prefetch distance 2 (each step touches a fresh 128B line; HBM
  // first-touch ~900cy must be covered by ~2 steps of work)
  f32x4 c0a, c0b, c1a, c1b;
  {
    int ro = s32 - WU; if (ro < 0) ro = 0;
    const float* p = xb + (size_t)ro * II + 4 * r0;
    c0a = *(const f32x4*)p; c0b = *(const f32x4*)(p + 16);
    int r1 = s32 + 1 - WU; if (r1 < 0) r1 = 0;
    const float* p1 = xb + (size_t)r1 * II + 4 * r0;
    c1a = *(const f32x4*)p1; c1b = *(const f32x4*)(p1 + 16);
  }

  // register-resident T fragments: tanh(h_init)=0
  bf16x8 Bt0 = 0, Bt1 = 0;

  for (int tt = 0; tt < NT; ++tt) {
    // prefetch x for tt+2
    f32x4 n2a, n2b;
    {
      int ro = s32 + tt + 2 - WU;
      if (ro < 0) ro = 0;
      if (ro > SS - 1) ro = SS - 1;
      const float* p = xb + (size_t)ro * II + 4 * r0;
      n2a = *(const f32x4*)p; n2b = *(const f32x4*)(p + 16);
    }
    bf16x8 Bx = pk8(c0a, c0b);  // B[k][s]: x_t[s=c]
    f32x4 t4[4];
    float psum = 0.0f;
#pragma unroll
    for (int m0 = 0; m0 < 4; ++m0) {
      f32x4 acc = bc4[m0];  // C-in = bc[j]
      acc = __builtin_amdgcn_mfma_f32_16x16x32_bf16(Ac[m0], Bx, acc, 0, 0, 0);
      acc = __builtin_amdgcn_mfma_f32_16x16x32_bf16(Ahh[m0][0], Bt0, acc, 0, 0, 0);
      acc = __builtin_amdgcn_mfma_f32_16x16x32_bf16(Ahh[m0][1], Bt1, acc, 0, 0, 0);
      h[m0] = ac4[m0] * h[m0] + ci4[m0] * acc;
      if (tt < WU) h[m0] = h[m0] * mz;
      f32x4 t;
#pragma unroll
      for (int r = 0; r < 4; ++r) {
        float e = fast_exp2(h[m0][r] * 2.885390081777927f);
        t[r] = 1.0f - 2.0f * fast_rcp(e + 1.0f);
        psum = fmaf(wo4[m0][r], t[r], psum);
      }
      t4[m0] = t;
    }
    // D->B alignment: next step's B-fragment is lane-local (no LDS!)
    Bt0 = pk8(t4[0], t4[1]);
    Bt1 = pk8(t4[2], t4[3]);
    if (tt >= WU) {
      psum += __shfl_xor(psum, 16);
      psum += __shfl_xor(psum, 32);
      if (l < 16) outp[tt - WU] = psum + bout;
    }
    c0a = c1a; c0b = c1b; c1a = n2a; c1b = n2b;
  }
}

extern "C" void kernel_launch(void* const* d_in, const int* in_sizes, int n_in,
                              void* d_out, int out_size, void* d_ws, size_t ws_size,
                              hipStream_t stream) {
  const float* x     = (const float*)d_in[0];
  const float* W_in  = (const float*)d_in[1];
  const float* b_in  = (const float*)d_in[2];
  const float* W_hh  = (const float*)d_in[3];
  const float* W_ih  = (const float*)d_in[4];
  const float* bias  = (const float*)d_in[5];
  const float* tau   = (const float*)d_in[6];
  const float* W_out = (const float*)d_in[7];
  const float* b_out = (const float*)d_in[8];
  float* out = (float*)d_out;
  char* ws = (char*)d_ws;
  float* Wc = (float*)ws;            // 8 KB
  float* bc = (float*)(ws + 8192);   // 256 B

  hipLaunchKernelGGL(prep_kernel, dim3(1), dim3(256), 0, stream,
                     W_in, b_in, W_ih, bias, Wc, bc);
  // 256 batches x 8 groups of 16 segments; 1 wave per block
  hipLaunchKernelGGL(fused_scan_kernel, dim3(BB * 8), dim3(64), 0, stream,
                     x, Wc, bc, W_hh, tau, W_out, b_out, out);
}

// Round 7
// 233.367 us; speedup vs baseline: 3.9717x; 1.0378x over previous
//
#include <hip/hip_runtime.h>
#include <hip/hip_bf16.h>
#include <cstdint>

typedef float f32x4 __attribute__((ext_vector_type(4)));
typedef short bf16x8 __attribute__((ext_vector_type(8)));

#define BB 256
#define SS 4096
#define II 32
#define HH 64
// 16 streams/wave via MFMA (swapped orientation: D[j][s], stream = column).
// SEGLEN=32, WU=8 warmup (contraction ~0.16/step -> init error 0.16^8~4e-7,
// below the bf16 noise floor; WU=32/16/8 measured identical absmax).
// Round 7: R6 measured ~4860 cy/step vs ~200 cy compute chain -> exposed
// x-gather latency on the serial chain (divergent 16-row gather + compiler
// collapsing the distance-2 rotating prefetch). Fixes:
//  (1) u = mfma(Ac,Bx,bc) computed at the BOTTOM of step t for step t+1 --
//      the x path is fully off the recurrence chain.
//  (2) 4-deep STATIC x pipeline (unroll-by-4, compile-time slot indices) --
//      loads issued ~3.5 step-times before consumption.
//  (3) warmup split out of the main loop (no per-step mask/store branches).
#define SEGLEN 32
#define WU 8
#define NT (WU + SEGLEN)

#define PINV(v) asm volatile("" : "+v"(v))

__device__ inline float fast_exp2(float x) {
#if __has_builtin(__builtin_amdgcn_exp2f)
  return __builtin_amdgcn_exp2f(x);
#else
  return exp2f(x);
#endif
}
__device__ inline float fast_rcp(float x) {
#if __has_builtin(__builtin_amdgcn_rcpf)
  return __builtin_amdgcn_rcpf(x);
#else
  return 1.0f / x;
#endif
}
__device__ inline unsigned short bfr(float f) {
  return __builtin_bit_cast(unsigned short, __float2bfloat16(f));
}
__device__ inline bf16x8 pk8(f32x4 a, f32x4 b) {
  bf16x8 r;
  r[0] = (short)bfr(a[0]); r[1] = (short)bfr(a[1]);
  r[2] = (short)bfr(a[2]); r[3] = (short)bfr(a[3]);
  r[4] = (short)bfr(b[0]); r[5] = (short)bfr(b[1]);
  r[6] = (short)bfr(b[2]); r[7] = (short)bfr(b[3]);
  return r;
}

// ---------------- prep: Wc = W_ih @ W_in  [64][32], bc = W_ih@b_in + bias ----------------
__global__ __launch_bounds__(256) void prep_kernel(
    const float* __restrict__ W_in, const float* __restrict__ b_in,
    const float* __restrict__ W_ih, const float* __restrict__ bias,
    float* __restrict__ Wc, float* __restrict__ bc) {
  int tid = threadIdx.x;
  int j = tid & 63;
  int iq = tid >> 6;
  float acc[8];
#pragma unroll
  for (int i = 0; i < 8; ++i) acc[i] = 0.f;
  const float* wih = W_ih + j * HH;
  for (int h = 0; h < HH; ++h) {
    float w = wih[h];
    const float* wr = W_in + h * II + iq * 8;
#pragma unroll
    for (int i = 0; i < 8; ++i) acc[i] = fmaf(w, wr[i], acc[i]);
  }
#pragma unroll
  for (int i = 0; i < 8; ++i) Wc[j * II + iq * 8 + i] = acc[i];
  if (iq == 0) {
    float s = 0.f;
    for (int h = 0; h < HH; ++h) s = fmaf(wih[h], b_in[h], s);
    bc[j] = s + bias[j];
  }
}

// ---------------- fused MFMA scan: 16 streams per wave, zero LDS ----------------
// Fragment maps (gfx950, 16x16x32 bf16; validated empirically R5/R6):
//   A[row][k]: row=(l&15)+16*m0; elem e -> k = kt*32 + (e<4 ? 4*(l>>4)+e : 16+4*(l>>4)+e-4)
//   B[k][n]:   n=l&15, same k map.  C/D: col=l&15, row=16*m0+4*(l>>4)+reg
// D->B identity: Bt0=pk8(t[m0=0],t[m0=1]), Bt1=pk8(t[2],t[3]) is lane-local.
__global__ __launch_bounds__(64, 2) void fused_scan_kernel(
    const float* __restrict__ x, const float* __restrict__ Wc,
    const float* __restrict__ bc, const float* __restrict__ W_hh,
    const float* __restrict__ tau, const float* __restrict__ W_out,
    const float* __restrict__ b_out, float* __restrict__ out) {
  int l = threadIdx.x;
  int c = l & 15, r0 = l >> 4;
  int blk = blockIdx.x;
  int b = blk >> 3;          // batch
  int g = blk & 7;           // 16-segment group within batch

  // W_hh A-fragments
  bf16x8 Ahh[4][2];
#pragma unroll
  for (int m0 = 0; m0 < 4; ++m0)
#pragma unroll
    for (int kt = 0; kt < 2; ++kt) {
      const float* p = W_hh + (size_t)(16 * m0 + c) * HH + kt * 32 + 4 * r0;
      Ahh[m0][kt] = pk8(*(const f32x4*)p, *(const f32x4*)(p + 16));
    }
  // Wc A-fragments (input projection, K=32 exactly)
  bf16x8 Ac[4];
#pragma unroll
  for (int m0 = 0; m0 < 4; ++m0) {
    const float* p = Wc + (size_t)(16 * m0 + c) * II + 4 * r0;
    Ac[m0] = pk8(*(const f32x4*)p, *(const f32x4*)(p + 16));
  }
#pragma unroll
  for (int m0 = 0; m0 < 4; ++m0) {
    PINV(Ahh[m0][0]); PINV(Ahh[m0][1]); PINV(Ac[m0]);
  }
  // per-lane j-coefficients: j = 16*m0 + 4*r0 + r
  f32x4 bc4[4], ci4[4], ac4[4], wo4[4], h[4];
#pragma unroll
  for (int m0 = 0; m0 < 4; ++m0) {
    int j0 = 16 * m0 + 4 * r0;
    bc4[m0] = *(const f32x4*)(bc + j0);
    f32x4 tv = *(const f32x4*)(tau + j0);
    f32x4 ci, ao;
#pragma unroll
    for (int r = 0; r < 4; ++r) { ci[r] = 1.0f / tv[r]; ao[r] = 1.0f - ci[r]; }
    ci4[m0] = ci; ac4[m0] = ao; h[m0] = 0.0f;
    wo4[m0] = *(const f32x4*)(W_out + j0);
  }
  float bout = b_out[0];
  // seg 0 (g==0, stream col 0) has no real history: force h=0 through warmup
  float mz = (g == 0 && c == 0) ? 0.0f : 1.0f;

  const float* xb = x + (size_t)b * (SS * II);
  int s32 = (g * 16 + c) * SEGLEN;   // global t of this lane's first real step
  int tb0 = s32 - WU;                // row of step tt is tb0 + tt (clamped)
  const float* px = xb + 4 * r0;
  float* outp = out + (size_t)b * SS + (size_t)(g * 16 + l) * SEGLEN;  // lanes<16

#define ROWCL(t) ({ int ro_ = (t) + tb0; ro_ = ro_ < 0 ? 0 : ro_; ro_ > SS - 1 ? SS - 1 : ro_; })

  // 4-deep x pipeline: slot i holds the x row of step tt with tt&3==i (next due)
  f32x4 sa[4], sb[4];
#pragma unroll
  for (int i = 0; i < 4; ++i) {
    const float* p = px + (size_t)ROWCL(i) * II;
    sa[i] = *(const f32x4*)p; sb[i] = *(const f32x4*)(p + 16);
  }
  // u for step 0 (consumes slot 0)
  f32x4 u[4];
  {
    bf16x8 Bx = pk8(sa[0], sb[0]);
#pragma unroll
    for (int m0 = 0; m0 < 4; ++m0)
      u[m0] = __builtin_amdgcn_mfma_f32_16x16x32_bf16(Ac[m0], Bx, bc4[m0], 0, 0, 0);
  }
  bf16x8 Bt0 = 0, Bt1 = 0;  // tanh(h_init) = 0

#define STEP(p, tt, MASKED, STORE)                                                     \
  {                                                                                    \
    { /* refill slot p with the x row of step (tt)+4 */                                \
      const float* pp_ = px + (size_t)ROWCL((tt) + 4) * II;                            \
      sa[p] = *(const f32x4*)pp_; sb[p] = *(const f32x4*)(pp_ + 16);                   \
    }                                                                                  \
    f32x4 t4_[4]; float psum = 0.0f;                                                   \
    _Pragma("unroll")                                                                  \
    for (int m0 = 0; m0 < 4; ++m0) {                                                   \
      f32x4 z_ = {0.f, 0.f, 0.f, 0.f};                                                 \
      f32x4 a1_ = __builtin_amdgcn_mfma_f32_16x16x32_bf16(Ahh[m0][0], Bt0, u[m0], 0, 0, 0); \
      f32x4 a2_ = __builtin_amdgcn_mfma_f32_16x16x32_bf16(Ahh[m0][1], Bt1, z_, 0, 0, 0);    \
      f32x4 acc_ = a1_ + a2_;                                                          \
      h[m0] = ac4[m0] * h[m0] + ci4[m0] * acc_;                                        \
      if (MASKED) h[m0] = h[m0] * mz;                                                  \
      _Pragma("unroll")                                                                \
      for (int r = 0; r < 4; ++r) {                                                    \
        float e_ = fast_exp2(h[m0][r] * 2.885390081777927f);                           \
        t4_[m0][r] = 1.0f - 2.0f * fast_rcp(e_ + 1.0f);                                \
        if (STORE) psum = fmaf(wo4[m0][r], t4_[m0][r], psum);                          \
      }                                                                                \
    }                                                                                  \
    Bt0 = pk8(t4_[0], t4_[1]); Bt1 = pk8(t4_[2], t4_[3]);                              \
    { /* off-chain: u for step (tt)+1 from slot (p+1)&3 */                             \
      bf16x8 Bx_ = pk8(sa[((p) + 1) & 3], sb[((p) + 1) & 3]);                          \
      _Pragma("unroll")                                                                \
      for (int m0 = 0; m0 < 4; ++m0)                                                   \
        u[m0] = __builtin_amdgcn_mfma_f32_16x16x32_bf16(Ac[m0], Bx_, bc4[m0], 0, 0, 0);\
    }                                                                                  \
    if (STORE) {                                                                       \
      psum += __shfl_xor(psum, 16);                                                    \
      psum += __shfl_xor(psum, 32);                                                    \
      if (l < 16) outp[(tt) - WU] = psum + bout;                                       \
    }                                                                                  \
  }

  // warmup: 8 steps, h masked for the no-history stream, no output
  for (int t4 = 0; t4 < WU; t4 += 4) {
#pragma unroll
    for (int p = 0; p < 4; ++p) STEP(p, t4 + p, true, false);
  }
  // main: 32 steps with fused output GEMV
  for (int t4 = WU; t4 < NT; t4 += 4) {
#pragma unroll
    for (int p = 0; p < 4; ++p) STEP(p, t4 + p, false, true);
  }
#undef STEP
#undef ROWCL
}

extern "C" void kernel_launch(void* const* d_in, const int* in_sizes, int n_in,
                              void* d_out, int out_size, void* d_ws, size_t ws_size,
                              hipStream_t stream) {
  const float* x     = (const float*)d_in[0];
  const float* W_in  = (const float*)d_in[1];
  const float* b_in  = (const float*)d_in[2];
  const float* W_hh  = (const float*)d_in[3];
  const float* W_ih  = (const float*)d_in[4];
  const float* bias  = (const float*)d_in[5];
  const float* tau   = (const float*)d_in[6];
  const float* W_out = (const float*)d_in[7];
  const float* b_out = (const float*)d_in[8];
  float* out = (float*)d_out;
  char* ws = (char*)d_ws;
  float* Wc = (float*)ws;            // 8 KB
  float* bc = (float*)(ws + 8192);   // 256 B

  hipLaunchKernelGGL(prep_kernel, dim3(1), dim3(256), 0, stream,
                     W_in, b_in, W_ih, bias, Wc, bc);
  // 256 batches x 8 groups of 16 segments; 1 wave per block
  hipLaunchKernelGGL(fused_scan_kernel, dim3(BB * 8), dim3(64), 0, stream,
                     x, Wc, bc, W_hh, tau, W_out, b_out, out);
}